// Round 2
// baseline (7914.088 us; speedup 1.0000x reference)
//
#include <hip/hip_runtime.h>

// InverseRecurrentLayer: 512-step scan  state = tanh(inputs[:,t,:]@R + state@Wt + bias)
// Wt alternates every 64 steps between inv(W) (== W^T, W orthogonal) and W.
// Persistent kernel, 64 blocks x 256 threads, hand-rolled grid barrier per step.
// Recurrent GEMM in split-bf16 (hi+lo) MFMA (3 passes) for f32-grade accuracy;
// input projection in plain bf16. All MFMA via builtins (no inline asm).

#define NBLK 64
#define NTHR 256
#define TSTEPS 512

typedef __attribute__((ext_vector_type(4))) float f32x4;
typedef __attribute__((ext_vector_type(8))) __bf16 bf16x8;

__device__ __forceinline__ f32x4 mfma16(bf16x8 a, bf16x8 b, f32x4 c){
  return __builtin_amdgcn_mfma_f32_16x16x32_bf16(a, b, c, 0, 0, 0);
}

// grid barrier: release(agent) -> flag=gen -> 64 lanes poll 64 flags -> acquire(agent)
__device__ __forceinline__ void gbar(unsigned* flags, unsigned gen){
  __syncthreads();
  if (threadIdx.x == 0){
    __builtin_amdgcn_fence(__ATOMIC_RELEASE, "agent");   // writeback: state/out -> coherent point
    __hip_atomic_store(flags + blockIdx.x, gen, __ATOMIC_RELAXED, __HIP_MEMORY_SCOPE_AGENT);
  }
  if (threadIdx.x < 64){
    int spins = 0;
    for (;;){
      unsigned v = __hip_atomic_load(flags + threadIdx.x, __ATOMIC_RELAXED, __HIP_MEMORY_SCOPE_AGENT);
      if (__all((int)(v >= gen))) break;
      __builtin_amdgcn_s_sleep(2);
      if (++spins > 4096) spins = 0;
    }
    __builtin_amdgcn_fence(__ATOMIC_ACQUIRE, "agent");   // invalidate: fresh state reads
  }
  __syncthreads();
}

// input-projection partials for step t: accin[m] += bf16(inputs[b,t,fq..fq+128]) @ rb
__device__ __forceinline__ void input_accum(f32x4 (&accin)[4], const float* __restrict__ inputs,
                                            const bf16x8 (&rb)[4], int t, int fq, int lr, int lg){
  #pragma unroll
  for (int kb = 0; kb < 4; ++kb){
    #pragma unroll
    for (int m = 0; m < 4; ++m){
      const float* ip = inputs + ((size_t)(m*16 + lr) * 512 + (size_t)t) * 512 + fq + kb*32 + lg*8;
      float4 xa = *(const float4*)ip;
      float4 xb = *(const float4*)(ip + 4);
      bf16x8 a;
      a[0] = (__bf16)xa.x; a[1] = (__bf16)xa.y; a[2] = (__bf16)xa.z; a[3] = (__bf16)xa.w;
      a[4] = (__bf16)xb.x; a[5] = (__bf16)xb.y; a[6] = (__bf16)xb.z; a[7] = (__bf16)xb.w;
      accin[m] = mfma16(a, rb[kb], accin[m]);
    }
  }
}

__global__ __launch_bounds__(NTHR, 1) void irl_scan(
    const float* __restrict__ inputs, const float* __restrict__ R,
    const float* __restrict__ W, const float* __restrict__ bias,
    const float* __restrict__ x0, float* __restrict__ out,
    __bf16* __restrict__ st_hi, __bf16* __restrict__ st_lo,
    unsigned* __restrict__ flags)
{
  // LDS: phase matrix slice [n=16][k=1024] bf16 hi+lo, XOR-swizzled (64KB)
  //    + cross-wave reduction buffer (24KB)
  __shared__ char ldsPhi[16 * 2048];
  __shared__ char ldsPlo[16 * 2048];
  __shared__ __attribute__((aligned(16))) float red2[4][4][16][24];

  const int tid = threadIdx.x;
  const int w  = tid >> 6;      // wave 0..3 : K-quarter owner, epilogue row-block owner
  const int l  = tid & 63;
  const int lr = l & 15;        // A row within 16-block / B col / D col
  const int lg = l >> 4;        // k-group (and D row-subgroup)
  const int col0 = blockIdx.x << 4;    // 16 output columns per block
  const int u = col0 + lr;
  const float bias_c = bias[u];
  const int kq = w << 8;        // recurrent K base (256/wave)
  const int fq = w << 7;        // input-proj K base (128/wave)

  // ---- R^T B-fragments in registers (time-invariant) ----
  bf16x8 rb[4];
  #pragma unroll
  for (int kb = 0; kb < 4; ++kb){
    bf16x8 t;
    #pragma unroll
    for (int j = 0; j < 8; ++j)
      t[j] = (__bf16)R[(size_t)(fq + kb*32 + lg*8 + j) * 1024 + u];
    rb[kb] = t;
  }

  // ---- state[0] <- x0 (this block's 16 columns, all 64 rows) ----
  for (int i = tid; i < 64 * 16; i += NTHR){
    int b = i >> 4, c = i & 15;
    float v = x0[col0 + c];
    __bf16 hi = (__bf16)v;
    __bf16 lo = (__bf16)(v - (float)hi);
    st_hi[b * 1024 + col0 + c] = hi;
    st_lo[b * 1024 + col0 + c] = lo;
  }

  // ---- input partials for t=0 (read-only data, safe before barrier) ----
  f32x4 zero = {0.f, 0.f, 0.f, 0.f};
  f32x4 accin[4];
  #pragma unroll
  for (int m = 0; m < 4; ++m) accin[m] = zero;
  input_accum(accin, inputs, rb, 0, fq, lr, lg);

  gbar(flags, 1u);   // state-init visible everywhere

  unsigned cur = 0;
  int pp = -1;
  for (int t = 0; t < TSTEPS; ++t){
    const int ph = (t >> 6) & 1;    // 1 -> use W, 0 -> use inv(W)=W^T
    if (ph != pp){
      // stage B[n][k] = Wt[k][col0+n] split hi/lo into LDS, XOR-swizzled.
      // ph=1 (W):   B[n][k] = W[k][col0+n]   (column slice)
      // ph=0 (W^T): B[n][k] = W[col0+n][k]   (row slice)
      for (int i = tid; i < 16 * 1024; i += NTHR){
        int n = i >> 10, k = i & 1023;
        float v = ph ? W[(size_t)k * 1024 + col0 + n]
                     : W[(size_t)(col0 + n) * 1024 + k];
        __bf16 hi = (__bf16)v;
        __bf16 lo = (__bf16)(v - (float)hi);
        int off = n * 2048 + (((unsigned)(k << 1)) ^ ((n & 7) << 4));
        *(__bf16*)(ldsPhi + off) = hi;
        *(__bf16*)(ldsPlo + off) = lo;
      }
      pp = ph;
      __syncthreads();
    }

    const __bf16* sh = st_hi + ((size_t)cur << 16);
    const __bf16* sl = st_lo + ((size_t)cur << 16);

    f32x4 acc[4];
    #pragma unroll
    for (int m = 0; m < 4; ++m) acc[m] = accin[m];

    // ---- recurrent split-bf16 passes over this wave's K-quarter ----
    #pragma unroll 2
    for (int kb = 0; kb < 8; ++kb){
      const int koff = kq + kb*32 + lg*8;
      const int lb = lr * 2048 + (((unsigned)(koff << 1)) ^ ((lr & 7) << 4));
      bf16x8 bh = *(const bf16x8*)(ldsPhi + lb);
      bf16x8 bl = *(const bf16x8*)(ldsPlo + lb);
      bf16x8 ah[4], al[4];
      #pragma unroll
      for (int m = 0; m < 4; ++m){
        ah[m] = *(const bf16x8*)(sh + (size_t)(m*16 + lr) * 1024 + koff);
        al[m] = *(const bf16x8*)(sl + (size_t)(m*16 + lr) * 1024 + koff);
      }
      #pragma unroll
      for (int m = 0; m < 4; ++m) acc[m] = mfma16(ah[m], bh, acc[m]);
      #pragma unroll
      for (int m = 0; m < 4; ++m) acc[m] = mfma16(ah[m], bl, acc[m]);
      #pragma unroll
      for (int m = 0; m < 4; ++m) acc[m] = mfma16(al[m], bh, acc[m]);
    }

    // ---- cross-wave K reduction via LDS ----
    #pragma unroll
    for (int m = 0; m < 4; ++m)
      *(f32x4*)&red2[w][m][lr][lg * 4] = acc[m];
    __syncthreads();

    f32x4 s = *(const f32x4*)&red2[0][w][lr][lg * 4];
    s = s + *(const f32x4*)&red2[1][w][lr][lg * 4];
    s = s + *(const f32x4*)&red2[2][w][lr][lg * 4];
    s = s + *(const f32x4*)&red2[3][w][lr][lg * 4];

    // ---- epilogue: wave w owns rows 16w..16w+15, row = 16w + lg*4 + j ----
    __bf16* nh = st_hi + ((size_t)(cur ^ 1u) << 16);
    __bf16* nl = st_lo + ((size_t)(cur ^ 1u) << 16);
    float* outp = out + (size_t)t * 65536 + (size_t)(w*16 + lg*4) * 1024 + u;
    #pragma unroll
    for (int j = 0; j < 4; ++j){
      float v = tanhf(s[j] + bias_c);
      outp[j * 1024] = v;
      __bf16 hi = (__bf16)v;
      __bf16 lo = (__bf16)(v - (float)hi);
      const int b = w*16 + lg*4 + j;
      nh[b * 1024 + u] = hi;
      nl[b * 1024 + u] = lo;
    }

    cur ^= 1u;
    if (t < TSTEPS - 1){
      // prefetch + pre-accumulate next step's input projection BEFORE the
      // barrier (read-only data; hides these loads/MFMAs under barrier wait)
      #pragma unroll
      for (int m = 0; m < 4; ++m) accin[m] = zero;
      input_accum(accin, inputs, rb, t + 1, fq, lr, lg);
      gbar(flags, (unsigned)(t + 2));
    }
  }
}

extern "C" void kernel_launch(void* const* d_in, const int* in_sizes, int n_in,
                              void* d_out, int out_size, void* d_ws, size_t ws_size,
                              hipStream_t stream){
  (void)in_sizes; (void)n_in; (void)out_size; (void)ws_size;
  const float* inputs = (const float*)d_in[0];   // [64,512,512] f32
  const float* R      = (const float*)d_in[1];   // [512,1024]  f32
  const float* W      = (const float*)d_in[2];   // [1024,1024] f32
  const float* bias   = (const float*)d_in[3];   // [1024]      f32
  const float* x0     = (const float*)d_in[4];   // [1024]      f32
  float* out = (float*)d_out;                    // [512,64,1024] f32

  char* ws = (char*)d_ws;
  unsigned* flags = (unsigned*)ws;                         // 4KB
  __bf16* st_hi = (__bf16*)(ws + 4096);                    // 2 x 64x1024 bf16
  __bf16* st_lo = (__bf16*)(ws + 4096 + 262144);           // 2 x 64x1024 bf16

  hipMemsetAsync(flags, 0, 4096, stream);
  hipLaunchKernelGGL(irl_scan, dim3(NBLK), dim3(NTHR), 0, stream,
                     inputs, R, W, bias, x0, out, st_hi, st_lo, flags);
}